// Round 5
// baseline (395.156 us; speedup 1.0000x reference)
//
#include <hip/hip_runtime.h>
#include <hip/hip_bf16.h>

#define NTOK 8192
#define DDIM 1024
#define NEXP 8
#define FDIM 2048
#define NKROW (NTOK * 2)   // 16384 expert-rows (top-2)
#define MAXT 80            // max 256-row tiles: 16384/256 + 8 rounding

typedef __attribute__((ext_vector_type(8))) short bf16x8;
typedef __attribute__((ext_vector_type(4))) short bf16x4;
typedef __attribute__((ext_vector_type(4))) float f32x4;

__device__ __forceinline__ unsigned short f2bf(float f) {
  union { float f; unsigned u; } v; v.f = f;
  unsigned r = v.u + 0x7fffu + ((v.u >> 16) & 1u);   // RNE
  return (unsigned short)(r >> 16);
}
__device__ __forceinline__ float bf2f(short s) {
  union { unsigned u; float f; } v; v.u = ((unsigned)(unsigned short)s) << 16; return v.f;
}

// async global->LDS, 16B per lane; LDS dest wave-uniform base (+lane*16 implicit)
__device__ __forceinline__ void gl16(const short* g, short* l) {
  __builtin_amdgcn_global_load_lds(
      (const __attribute__((address_space(1))) void*)g,
      (__attribute__((address_space(3))) void*)l, 16, 0, 0);
}

// ---------------- gate: fp64-accum logits, softmax top-2, renorm ----------------
__global__ void gate_kernel(const float* __restrict__ x, const float* __restrict__ gw,
                            int* __restrict__ tk_e, float* __restrict__ tk_w) {
  int wave = threadIdx.x >> 6, lane = threadIdx.x & 63;
  int n = blockIdx.x * 4 + wave;
  const float* xr = x + (size_t)n * DDIM;
  float xv[16];
#pragma unroll
  for (int i = 0; i < 16; i++) xv[i] = xr[lane + i * 64];
  float lg[NEXP];
#pragma unroll
  for (int e = 0; e < NEXP; e++) {
    const float* gr = gw + e * DDIM;
    double a = 0.0;
#pragma unroll
    for (int i = 0; i < 16; i++) a += (double)xv[i] * (double)gr[lane + i * 64];
#pragma unroll
    for (int s = 32; s > 0; s >>= 1) a += __shfl_xor(a, s, 64);
    lg[e] = (float)a;
  }
  if (lane == 0) {
    int i1 = 0; float b1 = lg[0];
#pragma unroll
    for (int e = 1; e < NEXP; e++) if (lg[e] > b1) { b1 = lg[e]; i1 = e; }
    int i2 = -1; float b2 = -3.4e38f;
#pragma unroll
    for (int e = 0; e < NEXP; e++) if (e != i1 && lg[e] > b2) { b2 = lg[e]; i2 = e; }
    float ex = __expf(b2 - b1);
    float inv = 1.0f / (1.0f + ex);
    tk_e[n * 2 + 0] = i1; tk_w[n * 2 + 0] = inv;
    tk_e[n * 2 + 1] = i2; tk_w[n * 2 + 1] = ex * inv;
  }
}

// ------------- deterministic counting-sort of (token,k) -> expert rows -------------
__global__ void build_index(const int* __restrict__ tk_e, int* __restrict__ tk_row,
                            int* __restrict__ offsets, int* __restrict__ tileE,
                            int* __restrict__ tileRow, int* __restrict__ nTiles) {
  __shared__ int cnt[256][NEXP];
  __shared__ int tot[NEXP];
  __shared__ int off_s[NEXP];
  int t = threadIdx.x;
  int c[NEXP];
#pragma unroll
  for (int e = 0; e < NEXP; e++) c[e] = 0;
  int base = t * 64;
  for (int i = 0; i < 64; i++) {
    int te = tk_e[base + i];
#pragma unroll
    for (int e = 0; e < NEXP; e++) c[e] += (te == e) ? 1 : 0;
  }
#pragma unroll
  for (int e = 0; e < NEXP; e++) cnt[t][e] = c[e];
  __syncthreads();
  if (t < NEXP) {
    int run = 0;
    for (int i = 0; i < 256; i++) { int v = cnt[i][t]; cnt[i][t] = run; run += v; }
    tot[t] = run;
  }
  __syncthreads();
  if (t == 0) {
    int o = 0, tc = 0;
    for (int e = 0; e < NEXP; e++) {
      off_s[e] = o; offsets[e] = o;
      int ce = tot[e];
      for (int i = 0; i < ce; i += 256) { tileE[tc] = e; tileRow[tc] = o + i; tc++; }
      o += ce;
    }
    offsets[NEXP] = o;
    nTiles[0] = tc;
    for (int q = tc; q < MAXT; q++) { tileE[q] = 0; tileRow[q] = 0; }
  }
  __syncthreads();
#pragma unroll
  for (int e = 0; e < NEXP; e++) c[e] = cnt[t][e] + off_s[e];
  for (int i = 0; i < 64; i++) {
    int te = tk_e[base + i];
    int r = 0;
#pragma unroll
    for (int e = 0; e < NEXP; e++) r += (te == e) ? c[e] : 0;
    tk_row[base + i] = r;
#pragma unroll
    for (int e = 0; e < NEXP; e++) c[e] += (te == e) ? 1 : 0;
  }
}

// ------------- gather token rows to bf16 xg -------------
__global__ void build_rows(const float* __restrict__ x,
                           const int* __restrict__ tk_row,
                           short* __restrict__ xg) {
  int idx = blockIdx.x;          // 0..NKROW-1 = n*2+k
  int n = idx >> 1;
  int row = tk_row[idx];
  const float4* xr = (const float4*)(x + (size_t)n * DDIM);
  float4 v = xr[threadIdx.x];
  bf16x4 o;
  o[0] = (short)f2bf(v.x); o[1] = (short)f2bf(v.y);
  o[2] = (short)f2bf(v.z); o[3] = (short)f2bf(v.w);
  *(bf16x4*)(xg + (size_t)row * DDIM + threadIdx.x * 4) = o;
}

// ------------- tiled transpose + fp32->bf16: in [R][C] -> out [C][R] per expert -------------
__global__ void transpose_cvt(const float* __restrict__ in, short* __restrict__ out,
                              int R, int C) {
  __shared__ float tile[64][65];
  int e = blockIdx.z;
  int cB = blockIdx.x * 64;
  int rB = blockIdx.y * 64;
  const float* src = in + (size_t)e * R * C;
  short* dst = out + (size_t)e * R * C;
  int t = threadIdx.x;
  int lr = t >> 4;
  int lc = (t & 15) * 4;
#pragma unroll
  for (int i = 0; i < 4; i++) {
    const float* p = src + (size_t)(rB + lr + i * 16) * C + cB + lc;
    float4 v = *(const float4*)p;
    tile[lr + i * 16][lc + 0] = v.x;
    tile[lr + i * 16][lc + 1] = v.y;
    tile[lr + i * 16][lc + 2] = v.z;
    tile[lr + i * 16][lc + 3] = v.w;
  }
  __syncthreads();
  int oc = t >> 2;
  int orr = (t & 3) * 16;
  bf16x8 o0, o1;
#pragma unroll
  for (int q = 0; q < 8; q++) {
    o0[q] = (short)f2bf(tile[orr + q][oc]);
    o1[q] = (short)f2bf(tile[orr + 8 + q][oc]);
  }
  short* op = dst + (size_t)(cB + oc) * R + rB + orr;
  *(bf16x8*)op = o0;
  *(bf16x8*)(op + 8) = o1;
}

// =====================================================================
// 256x256 GEMM core, 1-barrier-per-unit reg-pipelined schedule:
//   4 LDS slots of 32K-K units; stage lead 3 (slot (u+3)&3 == slot (u-1)&3,
//   whose reads finished before the previous barrier -> WAR safe).
//   unit u: stage(u+3); vmcnt(8); barrier;
//           [ds_read all 12 frags of slot u+1] || [32 MFMA on cur frags].
//   vmcnt(8) at unit u guarantees slot u+1 complete (allows u+2,u+3 in flight);
//   the barrier makes it an all-waves guarantee. MFMA never waits on lgkm.
// Conflict-free LDS swizzle (verified R4, conflicts==0): within each 1KB
// chunk, 16B-block (r,q) holds K-octet q ^ ((r>>1)&3), applied on the
// global SOURCE (linear gl16 dest, rule #21) and on the ds_read address.
// XCD grouping: bijective remap so each XCD owns a contiguous bx range
// -> B-panels (~1MB) resident in per-XCD L2.
// =====================================================================

#define GUNIT(CA, CB, NA, NB, u_, NT_, SA, SB) {                              \
    if ((u_) + 3 < (NT_)) { SA((u_) + 3); SB((u_) + 3);                       \
      asm volatile("s_waitcnt vmcnt(8)" ::: "memory"); }                      \
    else if ((u_) + 2 < (NT_)) { asm volatile("s_waitcnt vmcnt(4)" ::: "memory"); } \
    else { asm volatile("s_waitcnt vmcnt(0)" ::: "memory"); }                 \
    __builtin_amdgcn_s_barrier();                                             \
    if ((u_) + 1 < (NT_)) {                                                   \
      int sn_ = (((u_) + 1) & 3) * 16384;                                     \
      _Pragma("unroll")                                                       \
      for (int m_ = 0; m_ < 8; m_++) NA[m_] = *(const bf16x8*)(lds + sn_ + fragA + m_ * 512); \
      _Pragma("unroll")                                                       \
      for (int n_ = 0; n_ < 4; n_++) NB[n_] = *(const bf16x8*)(lds + sn_ + fragB + n_ * 512); \
    }                                                                         \
    __builtin_amdgcn_s_setprio(1);                                            \
    _Pragma("unroll")                                                         \
    for (int m_ = 0; m_ < 8; m_++)                                            \
      _Pragma("unroll")                                                       \
      for (int n_ = 0; n_ < 4; n_++)                                          \
        acc[m_][n_] = __builtin_amdgcn_mfma_f32_16x16x32_bf16(CA[m_], CB[n_], acc[m_][n_], 0, 0, 0); \
    __builtin_amdgcn_s_setprio(0);                                            \
  }

// ------------- GEMM1: xg[rows,1024] x {wg,wu} -> SwiGLU in-reg -> h[rows,2048] bf16 -------------
__global__ __launch_bounds__(512, 2) void gemm1(
    const short* __restrict__ xg, const short* __restrict__ wg, const short* __restrict__ wu,
    const int* __restrict__ tileE, const int* __restrict__ tileRow,
    const int* __restrict__ nTiles, const int* __restrict__ offsets,
    short* __restrict__ h) {
  // XCD-grouped bijective remap: nwg = 16*MAXT = 1280 = 8*160
  int flat = blockIdx.y * 16 + blockIdx.x;
  int wgid = (flat & 7) * 160 + (flat >> 3);
  int bx = wgid / MAXT, by = wgid % MAXT;
  if (by >= nTiles[0]) return;
  int e = tileE[by];
  int rowBase = tileRow[by];
  int segEnd = offsets[e + 1];
  int fB = bx * 128;            // 128 f's -> 256 tile cols: [quad][g16|g16|u16|u16]

  __shared__ __align__(16) char smem[131072];
  short* lds = (short*)smem;

  int tid = threadIdx.x;
  int w = tid >> 6, lane = tid & 63;
  int wr = w >> 2, wc = w & 3;
  int r15 = lane & 15, gg = lane >> 4;
  int srow = lane >> 2;
  int soct = (lane & 3) ^ ((lane >> 3) & 3);          // swizzled source K-octet
  int blk = r15 * 4 + (gg ^ ((r15 >> 1) & 3));        // swizzled 16B-block on read

  const short* aS0 = xg + (size_t)(rowBase + w * 32 + srow) * DDIM + soct * 8;
  const short* aS1 = aS0 + 16 * DDIM;
  const short* bmat = (w & 1) ? wu : wg;
  const short* bS0 = bmat + ((size_t)e * FDIM + fB + (w >> 1) * 32 + srow) * DDIM + soct * 8;
  const short* bS1 = bS0 + 16 * DDIM;

  int fragA = wr * 8 * 512 + blk * 8;            // + m*512 + slot*16384 (shorts)
  int fragB = 8192 + wc * 4 * 512 + blk * 8;     // + n*512 + slot*16384
  int dstA = w * 1024;
  int dstB = 8192 + w * 1024;

  f32x4 acc[8][4];
#pragma unroll
  for (int m = 0; m < 8; m++)
#pragma unroll
    for (int n = 0; n < 4; n++) acc[m][n] = (f32x4){0.f, 0.f, 0.f, 0.f};

#define STAGE_A1(u_) { int s_ = ((u_) & 3) * 16384; int k_ = (u_) * 32; \
    gl16(aS0 + k_, lds + s_ + dstA); gl16(aS1 + k_, lds + s_ + dstA + 512); }
#define STAGE_B1(u_) { int s_ = ((u_) & 3) * 16384; int k_ = (u_) * 32; \
    gl16(bS0 + k_, lds + s_ + dstB); gl16(bS1 + k_, lds + s_ + dstB + 512); }

  const int NT = DDIM / 32;   // 32
  STAGE_A1(0); STAGE_B1(0); STAGE_A1(1); STAGE_B1(1); STAGE_A1(2); STAGE_B1(2);
  asm volatile("s_waitcnt vmcnt(8)" ::: "memory");
  __builtin_amdgcn_s_barrier();

  bf16x8 fa0[8], fb0[4], fa1[8], fb1[4];
#pragma unroll
  for (int m = 0; m < 8; m++) fa0[m] = *(const bf16x8*)(lds + fragA + m * 512);
#pragma unroll
  for (int n = 0; n < 4; n++) fb0[n] = *(const bf16x8*)(lds + fragB + n * 512);

  for (int u = 0; u < NT; u += 2) {
    GUNIT(fa0, fb0, fa1, fb1, u, NT, STAGE_A1, STAGE_B1);
    GUNIT(fa1, fb1, fa0, fb0, u + 1, NT, STAGE_A1, STAGE_B1);
  }

  // ---- SwiGLU fully in-register: acc[m][0..1]=gate, acc[m][2..3]=up (same f cols)
#pragma unroll
  for (int m = 0; m < 8; m++) {
#pragma unroll
    for (int j = 0; j < 4; j++) {
      int grow = rowBase + wr * 128 + m * 16 + gg * 4 + j;
      if (grow < segEnd) {
        short* hp = h + (size_t)grow * FDIM + fB + wc * 32 + r15;
#pragma unroll
        for (int n = 0; n < 2; n++) {
          float g = acc[m][n][j];
          float uv = acc[m][n + 2][j];
          float hv = g / (1.0f + __expf(-g)) * uv;
          hp[n * 16] = (short)f2bf(hv);
        }
      }
    }
  }
#undef STAGE_A1
#undef STAGE_B1
}

// ------------- GEMM2: h[rows,2048] x wb2[d,f] -> outs[row,1024] bf16 (no atomics) -------------
__global__ __launch_bounds__(512, 2) void gemm2(
    const short* __restrict__ h, const short* __restrict__ w2,
    const int* __restrict__ tileE, const int* __restrict__ tileRow,
    const int* __restrict__ nTiles, const int* __restrict__ offsets,
    short* __restrict__ outs) {
  // XCD-grouped bijective remap: nwg = 4*MAXT = 320 = 8*40
  int flat = blockIdx.y * 4 + blockIdx.x;
  int wgid = (flat & 7) * 40 + (flat >> 3);
  int bx = wgid / MAXT, by = wgid % MAXT;
  if (by >= nTiles[0]) return;
  int e = tileE[by];
  int rowBase = tileRow[by];
  int segEnd = offsets[e + 1];
  int dB = bx * 256;

  __shared__ __align__(16) char smem[131072];
  short* lds = (short*)smem;

  int tid = threadIdx.x;
  int w = tid >> 6, lane = tid & 63;
  int wr = w >> 2, wc = w & 3;
  int r15 = lane & 15, gg = lane >> 4;
  int srow = lane >> 2;
  int soct = (lane & 3) ^ ((lane >> 3) & 3);
  int blk = r15 * 4 + (gg ^ ((r15 >> 1) & 3));

  const short* aS0 = h + (size_t)(rowBase + w * 32 + srow) * FDIM + soct * 8;
  const short* aS1 = aS0 + 16 * FDIM;
  const short* bS0 = w2 + ((size_t)e * DDIM + dB + w * 32 + srow) * FDIM + soct * 8;
  const short* bS1 = bS0 + 16 * FDIM;

  int fragA = wr * 8 * 512 + blk * 8;
  int fragB = 8192 + wc * 4 * 512 + blk * 8;
  int dstA = w * 1024;
  int dstB = 8192 + w * 1024;

  f32x4 acc[8][4];
#pragma unroll
  for (int m = 0; m < 8; m++)
#pragma unroll
    for (int n = 0; n < 4; n++) acc[m][n] = (f32x4){0.f, 0.f, 0.f, 0.f};

#define STAGE_A2(u_) { int s_ = ((u_) & 3) * 16384; int k_ = (u_) * 32; \
    gl16(aS0 + k_, lds + s_ + dstA); gl16(aS1 + k_, lds + s_ + dstA + 512); }
#define STAGE_B2(u_) { int s_ = ((u_) & 3) * 16384; int k_ = (u_) * 32; \
    gl16(bS0 + k_, lds + s_ + dstB); gl16(bS1 + k_, lds + s_ + dstB + 512); }

  const int NT = FDIM / 32;   // 64
  STAGE_A2(0); STAGE_B2(0); STAGE_A2(1); STAGE_B2(1); STAGE_A2(2); STAGE_B2(2);
  asm volatile("s_waitcnt vmcnt(8)" ::: "memory");
  __builtin_amdgcn_s_barrier();

  bf16x8 fa0[8], fb0[4], fa1[8], fb1[4];
#pragma unroll
  for (int m = 0; m < 8; m++) fa0[m] = *(const bf16x8*)(lds + fragA + m * 512);
#pragma unroll
  for (int n = 0; n < 4; n++) fb0[n] = *(const bf16x8*)(lds + fragB + n * 512);

  for (int u = 0; u < NT; u += 2) {
    GUNIT(fa0, fb0, fa1, fb1, u, NT, STAGE_A2, STAGE_B2);
    GUNIT(fa1, fb1, fa0, fb0, u + 1, NT, STAGE_A2, STAGE_B2);
  }

#pragma unroll
  for (int m = 0; m < 8; m++) {
#pragma unroll
    for (int j = 0; j < 4; j++) {
      int grow = rowBase + wr * 128 + m * 16 + gg * 4 + j;
      if (grow < segEnd) {
        short* op = outs + (size_t)grow * DDIM + dB + wc * 64 + r15;
#pragma unroll
        for (int n = 0; n < 4; n++)
          op[n * 16] = (short)f2bf(acc[m][n][j]);
      }
    }
  }
#undef STAGE_A2
#undef STAGE_B2
}

// ------------- combine: y[tok] = w0*outs[row0] + w1*outs[row1] -------------
__global__ void combine(const short* __restrict__ outs, const int* __restrict__ tk_row,
                        const float* __restrict__ tk_w, float* __restrict__ y) {
  int n = blockIdx.x;
  int t = threadIdx.x;
  int r0 = tk_row[2 * n], r1 = tk_row[2 * n + 1];
  float w0 = tk_w[2 * n], w1 = tk_w[2 * n + 1];
  bf16x4 a = *(const bf16x4*)(outs + (size_t)r0 * DDIM + t * 4);
  bf16x4 b = *(const bf16x4*)(outs + (size_t)r1 * DDIM + t * 4);
  float4 o;
  o.x = w0 * bf2f(a[0]) + w1 * bf2f(b[0]);
  o.y = w0 * bf2f(a[1]) + w1 * bf2f(b[1]);
  o.z = w0 * bf2f(a[2]) + w1 * bf2f(b[2]);
  o.w = w0 * bf2f(a[3]) + w1 * bf2f(b[3]);
  *(float4*)(y + (size_t)n * DDIM + t * 4) = o;
}

extern "C" void kernel_launch(void* const* d_in, const int* in_sizes, int n_in,
                              void* d_out, int out_size, void* d_ws, size_t ws_size,
                              hipStream_t stream) {
  const float* x      = (const float*)d_in[0];
  const float* gw     = (const float*)d_in[1];
  const float* w_gate = (const float*)d_in[2];
  const float* w_up   = (const float*)d_in[3];
  const float* w_down = (const float*)d_in[4];
  float* y = (float*)d_out;
  (void)in_sizes; (void)n_in; (void)ws_size; (void)out_size;

  char* ws = (char*)d_ws;
  size_t off = 0;
  auto alloc = [&](size_t bytes) -> void* {
    void* p = ws + off; off += (bytes + 255) & ~(size_t)255; return p;
  };
  short* wb1g      = (short*)alloc((size_t)NEXP * FDIM * DDIM * 2);   // [E][F][D] bf16
  short* wb1u      = (short*)alloc((size_t)NEXP * FDIM * DDIM * 2);   // [E][F][D] bf16
  short* wb2       = (short*)alloc((size_t)NEXP * DDIM * FDIM * 2);   // [E][D][F] bf16
  short* xg        = (short*)alloc((size_t)(NKROW + 256) * DDIM * 2); // gathered rows; REUSED as outs
  short* hbuf      = (short*)alloc((size_t)(NKROW + 256) * FDIM * 2); // SwiGLU output
  int*   tk_e      = (int*)alloc((size_t)NKROW * 4);
  float* tk_w      = (float*)alloc((size_t)NKROW * 4);
  int*   tk_row    = (int*)alloc((size_t)NKROW * 4);
  int*   tileE     = (int*)alloc(MAXT * 4);
  int*   tileRow   = (int*)alloc(MAXT * 4);
  int*   nTiles    = (int*)alloc(256);
  int*   offsets   = (int*)alloc(256);
  short* outs      = xg;   // xg is dead after gemm1; same size [NKROW+256][DDIM]

  transpose_cvt<<<dim3(FDIM / 64, DDIM / 64, NEXP), 256, 0, stream>>>(w_gate, wb1g, DDIM, FDIM);
  transpose_cvt<<<dim3(FDIM / 64, DDIM / 64, NEXP), 256, 0, stream>>>(w_up,   wb1u, DDIM, FDIM);
  transpose_cvt<<<dim3(DDIM / 64, FDIM / 64, NEXP), 256, 0, stream>>>(w_down, wb2,  FDIM, DDIM);
  gate_kernel<<<NTOK / 4, 256, 0, stream>>>(x, gw, tk_e, tk_w);
  build_index<<<1, 256, 0, stream>>>(tk_e, tk_row, offsets, tileE, tileRow, nTiles);
  build_rows<<<NKROW, 256, 0, stream>>>(x, tk_row, xg);
  gemm1<<<dim3(FDIM / 128, MAXT), 512, 0, stream>>>(xg, wb1g, wb1u, tileE, tileRow, nTiles, offsets, hbuf);
  gemm2<<<dim3(DDIM / 256, MAXT), 512, 0, stream>>>(hbuf, wb2, tileE, tileRow, nTiles, offsets, outs);
  combine<<<NTOK, 256, 0, stream>>>(outs, tk_row, tk_w, y);
}

// Round 6
// 393.085 us; speedup vs baseline: 1.0053x; 1.0053x over previous
//
#include <hip/hip_runtime.h>
#include <hip/hip_bf16.h>

#define NTOK 8192
#define DDIM 1024
#define NEXP 8
#define FDIM 2048
#define NKROW (NTOK * 2)   // 16384 expert-rows (top-2)
#define MAXT 80            // max 256-row tiles: 16384/256 + 8 rounding

typedef __attribute__((ext_vector_type(8))) short bf16x8;
typedef __attribute__((ext_vector_type(4))) short bf16x4;
typedef __attribute__((ext_vector_type(4))) float f32x4;

__device__ __forceinline__ unsigned short f2bf(float f) {
  union { float f; unsigned u; } v; v.f = f;
  unsigned r = v.u + 0x7fffu + ((v.u >> 16) & 1u);   // RNE
  return (unsigned short)(r >> 16);
}
__device__ __forceinline__ float bf2f(short s) {
  union { unsigned u; float f; } v; v.u = ((unsigned)(unsigned short)s) << 16; return v.f;
}

// async global->LDS, 16B per lane; LDS dest wave-uniform base (+lane*16 implicit)
__device__ __forceinline__ void gl16(const short* g, short* l) {
  __builtin_amdgcn_global_load_lds(
      (const __attribute__((address_space(1))) void*)g,
      (__attribute__((address_space(3))) void*)l, 16, 0, 0);
}

// ---------------- gate: fp64-accum logits, softmax top-2, renorm ----------------
__global__ void gate_kernel(const float* __restrict__ x, const float* __restrict__ gw,
                            int* __restrict__ tk_e, float* __restrict__ tk_w) {
  int wave = threadIdx.x >> 6, lane = threadIdx.x & 63;
  int n = blockIdx.x * 4 + wave;
  const float* xr = x + (size_t)n * DDIM;
  float xv[16];
#pragma unroll
  for (int i = 0; i < 16; i++) xv[i] = xr[lane + i * 64];
  float lg[NEXP];
#pragma unroll
  for (int e = 0; e < NEXP; e++) {
    const float* gr = gw + e * DDIM;
    double a = 0.0;
#pragma unroll
    for (int i = 0; i < 16; i++) a += (double)xv[i] * (double)gr[lane + i * 64];
#pragma unroll
    for (int s = 32; s > 0; s >>= 1) a += __shfl_xor(a, s, 64);
    lg[e] = (float)a;
  }
  if (lane == 0) {
    int i1 = 0; float b1 = lg[0];
#pragma unroll
    for (int e = 1; e < NEXP; e++) if (lg[e] > b1) { b1 = lg[e]; i1 = e; }
    int i2 = -1; float b2 = -3.4e38f;
#pragma unroll
    for (int e = 0; e < NEXP; e++) if (e != i1 && lg[e] > b2) { b2 = lg[e]; i2 = e; }
    float ex = __expf(b2 - b1);
    float inv = 1.0f / (1.0f + ex);
    tk_e[n * 2 + 0] = i1; tk_w[n * 2 + 0] = inv;
    tk_e[n * 2 + 1] = i2; tk_w[n * 2 + 1] = ex * inv;
  }
}

// ------------- deterministic counting-sort of (token,k) -> expert rows -------------
__global__ void build_index(const int* __restrict__ tk_e, int* __restrict__ tk_row,
                            int* __restrict__ offsets, int* __restrict__ tileE,
                            int* __restrict__ tileRow, int* __restrict__ nTiles) {
  __shared__ int cnt[256][NEXP];
  __shared__ int tot[NEXP];
  __shared__ int off_s[NEXP];
  int t = threadIdx.x;
  int c[NEXP];
#pragma unroll
  for (int e = 0; e < NEXP; e++) c[e] = 0;
  int base = t * 64;
  for (int i = 0; i < 64; i++) {
    int te = tk_e[base + i];
#pragma unroll
    for (int e = 0; e < NEXP; e++) c[e] += (te == e) ? 1 : 0;
  }
#pragma unroll
  for (int e = 0; e < NEXP; e++) cnt[t][e] = c[e];
  __syncthreads();
  if (t < NEXP) {
    int run = 0;
    for (int i = 0; i < 256; i++) { int v = cnt[i][t]; cnt[i][t] = run; run += v; }
    tot[t] = run;
  }
  __syncthreads();
  if (t == 0) {
    int o = 0, tc = 0;
    for (int e = 0; e < NEXP; e++) {
      off_s[e] = o; offsets[e] = o;
      int ce = tot[e];
      for (int i = 0; i < ce; i += 256) { tileE[tc] = e; tileRow[tc] = o + i; tc++; }
      o += ce;
    }
    offsets[NEXP] = o;
    nTiles[0] = tc;
    for (int q = tc; q < MAXT; q++) { tileE[q] = 0; tileRow[q] = 0; }
  }
  __syncthreads();
#pragma unroll
  for (int e = 0; e < NEXP; e++) c[e] = cnt[t][e] + off_s[e];
  for (int i = 0; i < 64; i++) {
    int te = tk_e[base + i];
    int r = 0;
#pragma unroll
    for (int e = 0; e < NEXP; e++) r += (te == e) ? c[e] : 0;
    tk_row[base + i] = r;
#pragma unroll
    for (int e = 0; e < NEXP; e++) c[e] += (te == e) ? 1 : 0;
  }
}

// ------------- gather token rows to bf16 xg -------------
__global__ void build_rows(const float* __restrict__ x,
                           const int* __restrict__ tk_row,
                           short* __restrict__ xg) {
  int idx = blockIdx.x;          // 0..NKROW-1 = n*2+k
  int n = idx >> 1;
  int row = tk_row[idx];
  const float4* xr = (const float4*)(x + (size_t)n * DDIM);
  float4 v = xr[threadIdx.x];
  bf16x4 o;
  o[0] = (short)f2bf(v.x); o[1] = (short)f2bf(v.y);
  o[2] = (short)f2bf(v.z); o[3] = (short)f2bf(v.w);
  *(bf16x4*)(xg + (size_t)row * DDIM + threadIdx.x * 4) = o;
}

// ------------- tiled transpose + fp32->bf16: in [R][C] -> out [C][R] per expert -------------
__global__ void transpose_cvt(const float* __restrict__ in, short* __restrict__ out,
                              int R, int C) {
  __shared__ float tile[64][65];
  int e = blockIdx.z;
  int cB = blockIdx.x * 64;
  int rB = blockIdx.y * 64;
  const float* src = in + (size_t)e * R * C;
  short* dst = out + (size_t)e * R * C;
  int t = threadIdx.x;
  int lr = t >> 4;
  int lc = (t & 15) * 4;
#pragma unroll
  for (int i = 0; i < 4; i++) {
    const float* p = src + (size_t)(rB + lr + i * 16) * C + cB + lc;
    float4 v = *(const float4*)p;
    tile[lr + i * 16][lc + 0] = v.x;
    tile[lr + i * 16][lc + 1] = v.y;
    tile[lr + i * 16][lc + 2] = v.z;
    tile[lr + i * 16][lc + 3] = v.w;
  }
  __syncthreads();
  int oc = t >> 2;
  int orr = (t & 3) * 16;
  bf16x8 o0, o1;
#pragma unroll
  for (int q = 0; q < 8; q++) {
    o0[q] = (short)f2bf(tile[orr + q][oc]);
    o1[q] = (short)f2bf(tile[orr + 8 + q][oc]);
  }
  short* op = dst + (size_t)(cB + oc) * R + rB + orr;
  *(bf16x8*)op = o0;
  *(bf16x8*)(op + 8) = o1;
}

// =====================================================================
// 256x256 GEMM core, 2-phase-per-unit barrier-aligned schedule:
//   4 LDS slots of BK=32 units; stage lead 3 (slot (u+3)&3 == (u-1)&3,
//   last read 3 barriers earlier -> WAR safe).
//   unit u, phase A: stage A(u+3); vmcnt(6); barrier;
//                    ds_read 8 frags of slot u+1; 16 MFMA (CA[0..3] x CB).
//   unit u, phase B: stage B(u+3); barrier;
//                    ds_read 4 frags of slot u+1; 16 MFMA (CA[4..7] x CB).
//   vmcnt ladder 6/4/0 proves slot u+1 landed before its first read at u's
//   phA (post-barrier). Frags reg-pipelined one unit ahead: MFMA clusters
//   never wait on lgkm. setprio(1) wraps each MFMA cluster (T5).
// Conflict-free LDS swizzle (verified R4: conflicts==0): within each 1KB
// chunk, 16B-block (r,q) holds K-octet q ^ ((r>>1)&3), applied on the
// global SOURCE (linear gl16 dest, rule #21) and on the ds_read address.
// NO XCD remap: default dispatch order keeps all f-panels of one row-band
// concurrent -> A-panel fetched once into L3 (R5 remap cost +70% FETCH).
// =====================================================================

#define GUNIT(CA, CB, NA, NB, u_, NT_, SA, SB) {                              \
    /* ---- phase A ---- */                                                   \
    if ((u_) + 3 < (NT_)) { SA((u_) + 3);                                     \
      asm volatile("s_waitcnt vmcnt(6)" ::: "memory"); }                      \
    else if ((u_) + 2 < (NT_)) { asm volatile("s_waitcnt vmcnt(4)" ::: "memory"); } \
    else { asm volatile("s_waitcnt vmcnt(0)" ::: "memory"); }                 \
    __builtin_amdgcn_s_barrier();                                             \
    if ((u_) + 1 < (NT_)) {                                                   \
      int sn_ = (((u_) + 1) & 3) * 16384;                                     \
      _Pragma("unroll")                                                       \
      for (int m_ = 0; m_ < 4; m_++) NA[m_] = *(const bf16x8*)(lds + sn_ + fragA + m_ * 512); \
      _Pragma("unroll")                                                       \
      for (int n_ = 0; n_ < 4; n_++) NB[n_] = *(const bf16x8*)(lds + sn_ + fragB + n_ * 512); \
    }                                                                         \
    __builtin_amdgcn_s_setprio(1);                                            \
    _Pragma("unroll")                                                         \
    for (int m_ = 0; m_ < 4; m_++)                                            \
      _Pragma("unroll")                                                       \
      for (int n_ = 0; n_ < 4; n_++)                                          \
        acc[m_][n_] = __builtin_amdgcn_mfma_f32_16x16x32_bf16(CA[m_], CB[n_], acc[m_][n_], 0, 0, 0); \
    __builtin_amdgcn_s_setprio(0);                                            \
    /* ---- phase B ---- */                                                   \
    if ((u_) + 3 < (NT_)) SB((u_) + 3);                                       \
    __builtin_amdgcn_s_barrier();                                             \
    if ((u_) + 1 < (NT_)) {                                                   \
      int sn_ = (((u_) + 1) & 3) * 16384;                                     \
      _Pragma("unroll")                                                       \
      for (int m_ = 0; m_ < 4; m_++) NA[4 + m_] = *(const bf16x8*)(lds + sn_ + fragA + (4 + m_) * 512); \
    }                                                                         \
    __builtin_amdgcn_s_setprio(1);                                            \
    _Pragma("unroll")                                                         \
    for (int m_ = 0; m_ < 4; m_++)                                            \
      _Pragma("unroll")                                                       \
      for (int n_ = 0; n_ < 4; n_++)                                          \
        acc[4 + m_][n_] = __builtin_amdgcn_mfma_f32_16x16x32_bf16(CA[4 + m_], CB[n_], acc[4 + m_][n_], 0, 0, 0); \
    __builtin_amdgcn_s_setprio(0);                                            \
  }

// ------------- GEMM1: xg[rows,1024] x {wg,wu} -> SwiGLU in-reg -> h[rows,2048] bf16 -------------
__global__ __launch_bounds__(512, 2) void gemm1(
    const short* __restrict__ xg, const short* __restrict__ wg, const short* __restrict__ wu,
    const int* __restrict__ tileE, const int* __restrict__ tileRow,
    const int* __restrict__ nTiles, const int* __restrict__ offsets,
    short* __restrict__ h) {
  if ((int)blockIdx.y >= nTiles[0]) return;
  int e = tileE[blockIdx.y];
  int rowBase = tileRow[blockIdx.y];
  int segEnd = offsets[e + 1];
  int fB = blockIdx.x * 128;    // 128 f's -> 256 tile cols: [quad][g16|g16|u16|u16]

  __shared__ __align__(16) char smem[131072];
  short* lds = (short*)smem;

  int tid = threadIdx.x;
  int w = tid >> 6, lane = tid & 63;
  int wr = w >> 2, wc = w & 3;
  int r15 = lane & 15, gg = lane >> 4;
  int srow = lane >> 2;
  int soct = (lane & 3) ^ ((lane >> 3) & 3);          // swizzled source K-octet
  int blk = r15 * 4 + (gg ^ ((r15 >> 1) & 3));        // swizzled 16B-block on read

  const short* aS0 = xg + (size_t)(rowBase + w * 32 + srow) * DDIM + soct * 8;
  const short* aS1 = aS0 + 16 * DDIM;
  const short* bmat = (w & 1) ? wu : wg;
  const short* bS0 = bmat + ((size_t)e * FDIM + fB + (w >> 1) * 32 + srow) * DDIM + soct * 8;
  const short* bS1 = bS0 + 16 * DDIM;

  int fragA = wr * 8 * 512 + blk * 8;            // + m*512 + slot*16384 (shorts)
  int fragB = 8192 + wc * 4 * 512 + blk * 8;     // + n*512 + slot*16384
  int dstA = w * 1024;
  int dstB = 8192 + w * 1024;

  f32x4 acc[8][4];
#pragma unroll
  for (int m = 0; m < 8; m++)
#pragma unroll
    for (int n = 0; n < 4; n++) acc[m][n] = (f32x4){0.f, 0.f, 0.f, 0.f};

#define STAGE_A1(u_) { int s_ = ((u_) & 3) * 16384; int k_ = (u_) * 32; \
    gl16(aS0 + k_, lds + s_ + dstA); gl16(aS1 + k_, lds + s_ + dstA + 512); }
#define STAGE_B1(u_) { int s_ = ((u_) & 3) * 16384; int k_ = (u_) * 32; \
    gl16(bS0 + k_, lds + s_ + dstB); gl16(bS1 + k_, lds + s_ + dstB + 512); }

  const int NT = DDIM / 32;   // 32
  STAGE_A1(0); STAGE_B1(0); STAGE_A1(1); STAGE_B1(1); STAGE_A1(2); STAGE_B1(2);
  asm volatile("s_waitcnt vmcnt(8)" ::: "memory");
  __builtin_amdgcn_s_barrier();

  bf16x8 fa0[8], fb0[4], fa1[8], fb1[4];
#pragma unroll
  for (int m = 0; m < 8; m++) fa0[m] = *(const bf16x8*)(lds + fragA + m * 512);
#pragma unroll
  for (int n = 0; n < 4; n++) fb0[n] = *(const bf16x8*)(lds + fragB + n * 512);

  for (int u = 0; u < NT; u += 2) {
    GUNIT(fa0, fb0, fa1, fb1, u, NT, STAGE_A1, STAGE_B1);
    GUNIT(fa1, fb1, fa0, fb0, u + 1, NT, STAGE_A1, STAGE_B1);
  }

  // ---- SwiGLU fully in-register: acc[m][0..1]=gate, acc[m][2..3]=up (same f cols)
#pragma unroll
  for (int m = 0; m < 8; m++) {
#pragma unroll
    for (int j = 0; j < 4; j++) {
      int grow = rowBase + wr * 128 + m * 16 + gg * 4 + j;
      if (grow < segEnd) {
        short* hp = h + (size_t)grow * FDIM + fB + wc * 32 + r15;
#pragma unroll
        for (int n = 0; n < 2; n++) {
          float g = acc[m][n][j];
          float uv = acc[m][n + 2][j];
          float hv = g / (1.0f + __expf(-g)) * uv;
          hp[n * 16] = (short)f2bf(hv);
        }
      }
    }
  }
#undef STAGE_A1
#undef STAGE_B1
}

// ------------- GEMM2: h[rows,2048] x wb2[d,f] -> outs[row,1024] bf16 (no atomics) -------------
__global__ __launch_bounds__(512, 2) void gemm2(
    const short* __restrict__ h, const short* __restrict__ w2,
    const int* __restrict__ tileE, const int* __restrict__ tileRow,
    const int* __restrict__ nTiles, const int* __restrict__ offsets,
    short* __restrict__ outs) {
  if ((int)blockIdx.y >= nTiles[0]) return;
  int e = tileE[blockIdx.y];
  int rowBase = tileRow[blockIdx.y];
  int segEnd = offsets[e + 1];
  int dB = blockIdx.x * 256;

  __shared__ __align__(16) char smem[131072];
  short* lds = (short*)smem;

  int tid = threadIdx.x;
  int w = tid >> 6, lane = tid & 63;
  int wr = w >> 2, wc = w & 3;
  int r15 = lane & 15, gg = lane >> 4;
  int srow = lane >> 2;
  int soct = (lane & 3) ^ ((lane >> 3) & 3);
  int blk = r15 * 4 + (gg ^ ((r15 >> 1) & 3));

  const short* aS0 = h + (size_t)(rowBase + w * 32 + srow) * FDIM + soct * 8;
  const short* aS1 = aS0 + 16 * FDIM;
  const short* bS0 = w2 + ((size_t)e * DDIM + dB + w * 32 + srow) * FDIM + soct * 8;
  const short* bS1 = bS0 + 16 * FDIM;

  int fragA = wr * 8 * 512 + blk * 8;
  int fragB = 8192 + wc * 4 * 512 + blk * 8;
  int dstA = w * 1024;
  int dstB = 8192 + w * 1024;

  f32x4 acc[8][4];
#pragma unroll
  for (int m = 0; m < 8; m++)
#pragma unroll
    for (int n = 0; n < 4; n++) acc[m][n] = (f32x4){0.f, 0.f, 0.f, 0.f};

#define STAGE_A2(u_) { int s_ = ((u_) & 3) * 16384; int k_ = (u_) * 32; \
    gl16(aS0 + k_, lds + s_ + dstA); gl16(aS1 + k_, lds + s_ + dstA + 512); }
#define STAGE_B2(u_) { int s_ = ((u_) & 3) * 16384; int k_ = (u_) * 32; \
    gl16(bS0 + k_, lds + s_ + dstB); gl16(bS1 + k_, lds + s_ + dstB + 512); }

  const int NT = FDIM / 32;   // 64
  STAGE_A2(0); STAGE_B2(0); STAGE_A2(1); STAGE_B2(1); STAGE_A2(2); STAGE_B2(2);
  asm volatile("s_waitcnt vmcnt(8)" ::: "memory");
  __builtin_amdgcn_s_barrier();

  bf16x8 fa0[8], fb0[4], fa1[8], fb1[4];
#pragma unroll
  for (int m = 0; m < 8; m++) fa0[m] = *(const bf16x8*)(lds + fragA + m * 512);
#pragma unroll
  for (int n = 0; n < 4; n++) fb0[n] = *(const bf16x8*)(lds + fragB + n * 512);

  for (int u = 0; u < NT; u += 2) {
    GUNIT(fa0, fb0, fa1, fb1, u, NT, STAGE_A2, STAGE_B2);
    GUNIT(fa1, fb1, fa0, fb0, u + 1, NT, STAGE_A2, STAGE_B2);
  }

#pragma unroll
  for (int m = 0; m < 8; m++) {
#pragma unroll
    for (int j = 0; j < 4; j++) {
      int grow = rowBase + wr * 128 + m * 16 + gg * 4 + j;
      if (grow < segEnd) {
        short* op = outs + (size_t)grow * DDIM + dB + wc * 64 + r15;
#pragma unroll
        for (int n = 0; n < 4; n++)
          op[n * 16] = (short)f2bf(acc[m][n][j]);
      }
    }
  }
#undef STAGE_A2
#undef STAGE_B2
}

// ------------- combine: y[tok] = w0*outs[row0] + w1*outs[row1] -------------
__global__ void combine(const short* __restrict__ outs, const int* __restrict__ tk_row,
                        const float* __restrict__ tk_w, float* __restrict__ y) {
  int n = blockIdx.x;
  int t = threadIdx.x;
  int r0 = tk_row[2 * n], r1 = tk_row[2 * n + 1];
  float w0 = tk_w[2 * n], w1 = tk_w[2 * n + 1];
  bf16x4 a = *(const bf16x4*)(outs + (size_t)r0 * DDIM + t * 4);
  bf16x4 b = *(const bf16x4*)(outs + (size_t)r1 * DDIM + t * 4);
  float4 o;
  o.x = w0 * bf2f(a[0]) + w1 * bf2f(b[0]);
  o.y = w0 * bf2f(a[1]) + w1 * bf2f(b[1]);
  o.z = w0 * bf2f(a[2]) + w1 * bf2f(b[2]);
  o.w = w0 * bf2f(a[3]) + w1 * bf2f(b[3]);
  *(float4*)(y + (size_t)n * DDIM + t * 4) = o;
}

extern "C" void kernel_launch(void* const* d_in, const int* in_sizes, int n_in,
                              void* d_out, int out_size, void* d_ws, size_t ws_size,
                              hipStream_t stream) {
  const float* x      = (const float*)d_in[0];
  const float* gw     = (const float*)d_in[1];
  const float* w_gate = (const float*)d_in[2];
  const float* w_up   = (const float*)d_in[3];
  const float* w_down = (const float*)d_in[4];
  float* y = (float*)d_out;
  (void)in_sizes; (void)n_in; (void)ws_size; (void)out_size;

  char* ws = (char*)d_ws;
  size_t off = 0;
  auto alloc = [&](size_t bytes) -> void* {
    void* p = ws + off; off += (bytes + 255) & ~(size_t)255; return p;
  };
  short* wb1g      = (short*)alloc((size_t)NEXP * FDIM * DDIM * 2);   // [E][F][D] bf16
  short* wb1u      = (short*)alloc((size_t)NEXP * FDIM * DDIM * 2);   // [E][F][D] bf16
  short* wb2       = (short*)alloc((size_t)NEXP * DDIM * FDIM * 2);   // [E][D][F] bf16
  short* xg        = (short*)alloc((size_t)(NKROW + 256) * DDIM * 2); // gathered rows; REUSED as outs
  short* hbuf      = (short*)alloc((size_t)(NKROW + 256) * FDIM * 2); // SwiGLU output
  int*   tk_e      = (int*)alloc((size_t)NKROW * 4);
  float* tk_w      = (float*)alloc((size_t)NKROW * 4);
  int*   tk_row    = (int*)alloc((size_t)NKROW * 4);
  int*   tileE     = (int*)alloc(MAXT * 4);
  int*   tileRow   = (int*)alloc(MAXT * 4);
  int*   nTiles    = (int*)alloc(256);
  int*   offsets   = (int*)alloc(256);
  short* outs      = xg;   // xg is dead after gemm1; same size [NKROW+256][DDIM]

  transpose_cvt<<<dim3(FDIM / 64, DDIM / 64, NEXP), 256, 0, stream>>>(w_gate, wb1g, DDIM, FDIM);
  transpose_cvt<<<dim3(FDIM / 64, DDIM / 64, NEXP), 256, 0, stream>>>(w_up,   wb1u, DDIM, FDIM);
  transpose_cvt<<<dim3(DDIM / 64, FDIM / 64, NEXP), 256, 0, stream>>>(w_down, wb2,  FDIM, DDIM);
  gate_kernel<<<NTOK / 4, 256, 0, stream>>>(x, gw, tk_e, tk_w);
  build_index<<<1, 256, 0, stream>>>(tk_e, tk_row, offsets, tileE, tileRow, nTiles);
  build_rows<<<NKROW, 256, 0, stream>>>(x, tk_row, xg);
  gemm1<<<dim3(FDIM / 128, MAXT), 512, 0, stream>>>(xg, wb1g, wb1u, tileE, tileRow, nTiles, offsets, hbuf);
  gemm2<<<dim3(DDIM / 256, MAXT), 512, 0, stream>>>(hbuf, wb2, tileE, tileRow, nTiles, offsets, outs);
  combine<<<NTOK, 256, 0, stream>>>(outs, tk_row, tk_w, y);
}